// Round 1
// baseline (1303.509 us; speedup 1.0000x reference)
//
#include <hip/hip_runtime.h>

#define N_ROWS 32768
#define DIM    256
#define NE     1024
#define BM     64
#define BN     64

// ws layout (float offsets)
#define OFF_LOSS 0
#define OFF_N    1
#define OFF_CSQ  256
#define OFF_CNT  2048
#define OFF_SUM  4096
#define WS_FLOATS (OFF_SUM + NE * DIM)

// out layout (float offsets)
#define O_ZQ   0
#define O_LOSS 8388608
#define O_IDX  8388609
#define O_NCB  8421377
#define O_NCS  8683521
#define O_NES  8684545

// ---------------- kernel 1: codebook squared norms ----------------
__global__ __launch_bounds__(256) void csq_kernel(const float* __restrict__ cb,
                                                  float* __restrict__ csq) {
    int e    = blockIdx.x * 4 + (threadIdx.x >> 6);
    int lane = threadIdx.x & 63;
    float4 v = *(const float4*)(cb + e * DIM + lane * 4);
    float s  = v.x * v.x + v.y * v.y + v.z * v.z + v.w * v.w;
#pragma unroll
    for (int off = 32; off >= 1; off >>= 1) s += __shfl_down(s, off, 64);
    if (lane == 0) csq[e] = s;
}

// ---------------- kernel 2: distances + argmin + gather + stats ----------------
__global__ __launch_bounds__(256, 2) void vq_main(const float* __restrict__ z,
                                                  const float* __restrict__ cb,
                                                  const float* __restrict__ csq,
                                                  float* __restrict__ out_zq,
                                                  float* __restrict__ out_idx,
                                                  float* __restrict__ ws_cnt,
                                                  float* __restrict__ ws_sum,
                                                  float* __restrict__ ws_loss) {
    __shared__ float xs[DIM * BM];   // K-major x tile: xs[k][r], 64 KB
    __shared__ float cs[64 * BN];    // K-major code tile chunk: cs[k][c], 16 KB

    const int tid  = threadIdx.x;
    const int row0 = blockIdx.x * BM;

    // ---- stage x tile (K-major transpose write; lanes r-consecutive => conflict-free)
    {
        int r = tid & 63, seg = tid >> 6;
        const float* src = z + (row0 + r) * DIM + seg * 64;
#pragma unroll
        for (int j = 0; j < 16; ++j) {
            float4 v = ((const float4*)src)[j];
            int k = seg * 64 + j * 4;
            xs[(k + 0) * BM + r] = v.x;
            xs[(k + 1) * BM + r] = v.y;
            xs[(k + 2) * BM + r] = v.z;
            xs[(k + 3) * BM + r] = v.w;
        }
    }

    const int tx = tid & 15, ty = tid >> 4;
    const float* xbase = xs + ty * 4;
    const float* cbase = cs + tx * 4;

    float bv[4];
    int   bi[4];
#pragma unroll
    for (int i = 0; i < 4; ++i) { bv[i] = 3.4e38f; bi[i] = 0; }

    for (int ec = 0; ec < NE / BN; ++ec) {
        int e0 = ec * BN;
        float acc[4][4];
#pragma unroll
        for (int i = 0; i < 4; ++i)
#pragma unroll
            for (int j = 0; j < 4; ++j) acc[i][j] = 0.f;

        for (int kk = 0; kk < 4; ++kk) {
            __syncthreads();   // protect cs (also covers xs staging on first pass)
            {
                int c = tid & 63, kq = tid >> 6;
                const float* src = cb + (e0 + c) * DIM + kk * 64 + kq * 16;
#pragma unroll
                for (int j = 0; j < 4; ++j) {
                    float4 v = ((const float4*)src)[j];
                    int k = kq * 16 + j * 4;
                    cs[(k + 0) * BN + c] = v.x;
                    cs[(k + 1) * BN + c] = v.y;
                    cs[(k + 2) * BN + c] = v.z;
                    cs[(k + 3) * BN + c] = v.w;
                }
            }
            __syncthreads();
            int kb = kk * 64;
#pragma unroll 16
            for (int k = 0; k < 64; ++k) {
                float4 xa = *(const float4*)(xbase + (kb + k) * BM);
                float4 cv = *(const float4*)(cbase + k * BN);
                float xr[4] = {xa.x, xa.y, xa.z, xa.w};
                float cc[4] = {cv.x, cv.y, cv.z, cv.w};
#pragma unroll
                for (int i = 0; i < 4; ++i)
#pragma unroll
                    for (int j = 0; j < 4; ++j)
                        acc[i][j] = fmaf(xr[i], cc[j], acc[i][j]);
            }
        }
        // argmin update (z_sq omitted: constant per row)
#pragma unroll
        for (int j = 0; j < 4; ++j) {
            int e = e0 + tx * 4 + j;
            float cq = csq[e];
#pragma unroll
            for (int i = 0; i < 4; ++i) {
                float d = cq - 2.0f * acc[i][j];
                if (d < bv[i] || (d == bv[i] && e < bi[i])) { bv[i] = d; bi[i] = e; }
            }
        }
    }

    // lexicographic (val,idx) min across the 16 tx-lanes of each ty-group
#pragma unroll
    for (int i = 0; i < 4; ++i) {
        for (int off = 8; off >= 1; off >>= 1) {
            float ov = __shfl_xor(bv[i], off, 16);
            int   oi = __shfl_xor(bi[i], off, 16);
            if (ov < bv[i] || (ov == bv[i] && oi < bi[i])) { bv[i] = ov; bi[i] = oi; }
        }
    }

    __syncthreads();                  // cs no longer needed as code tile
    int* ridx = (int*)cs;             // alias
    if (tx == 0) {
#pragma unroll
        for (int i = 0; i < 4; ++i) {
            int r = ty * 4 + i;
            ridx[r] = bi[i];
            out_idx[row0 + r] = (float)bi[i];
            atomicAdd(&ws_cnt[bi[i]], 1.0f);
        }
    }
    __syncthreads();

    // gather z_q, commitment loss, embed-sum scatter
    float lsum = 0.f;
    {
        int r = tid >> 2, part = tid & 3;
        int e = ridx[r];
        const float4* crow = (const float4*)(cb + e * DIM + part * 64);
        const float4* zrow = (const float4*)(z + (row0 + r) * DIM + part * 64);
        float4*       qrow = (float4*)(out_zq + (row0 + r) * DIM + part * 64);
        float*        srow = ws_sum + e * DIM + part * 64;
#pragma unroll
        for (int j = 0; j < 16; ++j) {
            float4 c4 = crow[j];
            float4 z4 = zrow[j];
            qrow[j] = c4;
            float dx = z4.x - c4.x, dy = z4.y - c4.y;
            float dz = z4.z - c4.z, dw = z4.w - c4.w;
            lsum += dx * dx + dy * dy + dz * dz + dw * dw;
            atomicAdd(srow + j * 4 + 0, z4.x);
            atomicAdd(srow + j * 4 + 1, z4.y);
            atomicAdd(srow + j * 4 + 2, z4.z);
            atomicAdd(srow + j * 4 + 3, z4.w);
        }
    }
#pragma unroll
    for (int off = 32; off >= 1; off >>= 1) lsum += __shfl_down(lsum, off, 64);
    float* lred = cs + 128;           // alias (beyond ridx)
    if ((tid & 63) == 0) lred[tid >> 6] = lsum;
    __syncthreads();
    if (tid == 0) atomicAdd(ws_loss, lred[0] + lred[1] + lred[2] + lred[3]);
}

// ---------------- kernel 3a: cluster-size EMA, n, loss ----------------
__global__ __launch_bounds__(1024) void finalize_a(const float* __restrict__ ema_cs,
                                                   float* __restrict__ ws,
                                                   float* __restrict__ out_ncs,
                                                   float* __restrict__ out_loss) {
    __shared__ float red[16];
    int tid = threadIdx.x;
    float cnt = ws[OFF_CNT + tid];
    float ncs = 0.99f * ema_cs[tid] + 0.01f * cnt;
    out_ncs[tid] = ncs;
    float s = ncs;
#pragma unroll
    for (int off = 32; off >= 1; off >>= 1) s += __shfl_down(s, off, 64);
    if ((tid & 63) == 0) red[tid >> 6] = s;
    __syncthreads();
    if (tid == 0) {
        float n = 0.f;
#pragma unroll
        for (int w = 0; w < 16; ++w) n += red[w];
        ws[OFF_N] = n;
        out_loss[0] = 0.5f * ws[OFF_LOSS] / (float)(N_ROWS * DIM);
    }
}

// ---------------- kernel 3b: embed-sum EMA + codebook update ----------------
__global__ __launch_bounds__(256) void finalize_b(const float* __restrict__ ema_sum,
                                                  const float* __restrict__ ws,
                                                  const float* __restrict__ out_ncs,
                                                  float* __restrict__ out_nes,
                                                  float* __restrict__ out_ncb) {
    int e = blockIdx.x, d = threadIdx.x;
    float bsum = ws[OFF_SUM + e * DIM + d];
    float nes  = 0.99f * ema_sum[e * DIM + d] + 0.01f * bsum;
    out_nes[e * DIM + d] = nes;
    float ncs = out_ncs[e];
    float n   = ws[OFF_N];
    float sm  = (ncs + 1e-5f) / (n + NE * 1e-5f) * n;
    out_ncb[e * DIM + d] = nes / sm;
}

extern "C" void kernel_launch(void* const* d_in, const int* in_sizes, int n_in,
                              void* d_out, int out_size, void* d_ws, size_t ws_size,
                              hipStream_t stream) {
    const float* z_e      = (const float*)d_in[0];
    const float* codebook = (const float*)d_in[1];
    const float* ema_cs   = (const float*)d_in[2];
    const float* ema_sum  = (const float*)d_in[3];
    float* out = (float*)d_out;
    float* ws  = (float*)d_ws;

    hipMemsetAsync(d_ws, 0, (size_t)WS_FLOATS * sizeof(float), stream);

    csq_kernel<<<NE / 4, 256, 0, stream>>>(codebook, ws + OFF_CSQ);

    vq_main<<<N_ROWS / BM, 256, 0, stream>>>(z_e, codebook, ws + OFF_CSQ,
                                             out + O_ZQ, out + O_IDX,
                                             ws + OFF_CNT, ws + OFF_SUM,
                                             ws + OFF_LOSS);

    finalize_a<<<1, 1024, 0, stream>>>(ema_cs, ws, out + O_NCS, out + O_LOSS);

    finalize_b<<<NE, 256, 0, stream>>>(ema_sum, ws, out + O_NCS,
                                       out + O_NES, out + O_NCB);
}

// Round 2
// 692.346 us; speedup vs baseline: 1.8827x; 1.8827x over previous
//
#include <hip/hip_runtime.h>

typedef unsigned long long u64;
typedef unsigned int u32;

#define N_ROWS 32768
#define DIM    256
#define NE     1024

// out layout (float offsets)
#define O_ZQ   0
#define O_LOSS 8388608
#define O_IDX  8388609
#define O_NCB  8421377
#define O_NCS  8683521
#define O_NES  8684545

// ws layout (float offsets)
#define OFF_LOSS   0
#define OFF_N      1
#define OFF_CSQ    64
#define OFF_CNT    1088
#define OFF_FILL   2112      // int[1024]
#define OFF_BASE   3200      // int[1024]
#define OFF_IDX    4224      // int[32768]
#define OFF_BUCKET 36992     // int[32768]
#define OFF_KEY    69888     // u64[32768] (byte offset 279552, 8B aligned)

// ---------------- codebook squared norms ----------------
__global__ __launch_bounds__(256) void csq_kernel(const float* __restrict__ cb,
                                                  float* __restrict__ csq) {
    int e    = blockIdx.x * 4 + (threadIdx.x >> 6);
    int lane = threadIdx.x & 63;
    float4 v = *(const float4*)(cb + (size_t)e * DIM + lane * 4);
    float s  = v.x * v.x + v.y * v.y + v.z * v.z + v.w * v.w;
#pragma unroll
    for (int off = 32; off >= 1; off >>= 1) s += __shfl_down(s, off, 64);
    if (lane == 0) csq[e] = s;
}

// ---------------- GEMM + per-row argmin via packed u64 atomicMin ----------------
__global__ __launch_bounds__(256, 4) void gemm_argmin(const float* __restrict__ z,
                                                      const float* __restrict__ cb,
                                                      const float* __restrict__ ws_csq,
                                                      u64* __restrict__ keys) {
    __shared__ float xs[32][128];   // K-major x tile chunk, 16 KB
    __shared__ float cs[32][128];   // K-major code tile chunk, 16 KB

    const int tid  = threadIdx.x;
    const int row0 = blockIdx.x * 128;
    const int e0   = blockIdx.y * 128;
    const int tx   = tid & 15, ty = tid >> 4;
    const int skq  = tid & 7,  sr = tid >> 3;    // staging: float4-idx along k, row group

    float acc[8][8];
#pragma unroll
    for (int i = 0; i < 8; ++i)
#pragma unroll
        for (int j = 0; j < 8; ++j) acc[i][j] = 0.f;

    for (int kc = 0; kc < DIM; kc += 32) {
        __syncthreads();
        // stage x chunk (transpose to K-major; 8-lane-contiguous 128B global segments)
#pragma unroll
        for (int j = 0; j < 4; ++j) {
            int r = sr + j * 32;
            float4 v = *(const float4*)(z + (size_t)(row0 + r) * DIM + kc + skq * 4);
            xs[skq * 4 + 0][r] = v.x; xs[skq * 4 + 1][r] = v.y;
            xs[skq * 4 + 2][r] = v.z; xs[skq * 4 + 3][r] = v.w;
        }
        // stage codebook chunk
#pragma unroll
        for (int j = 0; j < 4; ++j) {
            int c = sr + j * 32;
            float4 v = *(const float4*)(cb + (size_t)(e0 + c) * DIM + kc + skq * 4);
            cs[skq * 4 + 0][c] = v.x; cs[skq * 4 + 1][c] = v.y;
            cs[skq * 4 + 2][c] = v.z; cs[skq * 4 + 3][c] = v.w;
        }
        __syncthreads();
#pragma unroll 2
        for (int k = 0; k < 32; ++k) {
            float4 xa  = *(const float4*)(&xs[k][ty * 4]);        // broadcast over tx
            float4 xb  = *(const float4*)(&xs[k][64 + ty * 4]);
            float4 ca  = *(const float4*)(&cs[k][tx * 4]);        // 2-way (free) over lanes
            float4 cb4 = *(const float4*)(&cs[k][64 + tx * 4]);
            float xr[8] = {xa.x, xa.y, xa.z, xa.w, xb.x, xb.y, xb.z, xb.w};
            float cc[8] = {ca.x, ca.y, ca.z, ca.w, cb4.x, cb4.y, cb4.z, cb4.w};
#pragma unroll
            for (int i = 0; i < 8; ++i)
#pragma unroll
                for (int j = 0; j < 8; ++j)
                    acc[i][j] = fmaf(xr[i], cc[j], acc[i][j]);
        }
    }

    // distances (z_sq term constant per row: omitted) + lex argmin
    float cq[8];
#pragma unroll
    for (int j = 0; j < 8; ++j) {
        int e = e0 + ((j < 4) ? tx * 4 + j : 64 + tx * 4 + (j - 4));
        cq[j] = ws_csq[e];
    }
#pragma unroll
    for (int i = 0; i < 8; ++i) {
        float bv = 3.4e38f; int bi = 0x7fffffff;
#pragma unroll
        for (int j = 0; j < 8; ++j) {
            int e = e0 + ((j < 4) ? tx * 4 + j : 64 + tx * 4 + (j - 4));
            float d = fmaf(-2.0f, acc[i][j], cq[j]);
            if (d < bv || (d == bv && e < bi)) { bv = d; bi = e; }
        }
        // lex (val,idx) min across the 16 tx-lanes of this row group
#pragma unroll
        for (int off = 8; off >= 1; off >>= 1) {
            float ov = __shfl_xor(bv, off, 16);
            int   oi = __shfl_xor(bi, off, 16);
            if (ov < bv || (ov == bv && oi < bi)) { bv = ov; bi = oi; }
        }
        if (tx == 0) {
            int r = row0 + ((i < 4) ? ty * 4 + i : 64 + ty * 4 + (i - 4));
            u32 b = __float_as_uint(bv);
            u32 m = (b & 0x80000000u) ? ~b : (b | 0x80000000u);  // order-preserving map
            u64 key = ((u64)m << 10) | (u32)bi;                  // exact (val, idx) lex order
            atomicMin(&keys[r], key);
        }
    }
}

// ---------------- combine argmin + gather z_q + commitment loss + counts ----------------
__global__ __launch_bounds__(256) void combine_gather(const float* __restrict__ z,
                                                      const float* __restrict__ cb,
                                                      float* __restrict__ out_zq,
                                                      float* __restrict__ out_idx,
                                                      float* __restrict__ ws) {
    __shared__ int   sidx[64];
    __shared__ float lred[4];
    const int tid  = threadIdx.x;
    const int row0 = blockIdx.x * 64;

    if (tid < 64) {
        const u64* keys = (const u64*)(ws + OFF_KEY);
        u64 key = keys[row0 + tid];
        int idx = (int)(key & 1023u);
        sidx[tid] = idx;
        out_idx[row0 + tid] = (float)idx;
        ((int*)ws)[OFF_IDX + row0 + tid] = idx;
        atomicAdd(&ws[OFF_CNT + idx], 1.0f);
    }
    __syncthreads();

    float lsum = 0.f;
    {
        int r = tid >> 2, part = tid & 3;
        int e = sidx[r];
        const float4* crow = (const float4*)(cb + (size_t)e * DIM + part * 64);
        const float4* zrow = (const float4*)(z + (size_t)(row0 + r) * DIM + part * 64);
        float4*       qrow = (float4*)(out_zq + (size_t)(row0 + r) * DIM + part * 64);
#pragma unroll
        for (int j = 0; j < 16; ++j) {
            float4 c4 = crow[j];
            float4 z4 = zrow[j];
            qrow[j] = c4;
            float dx = z4.x - c4.x, dy = z4.y - c4.y;
            float dz = z4.z - c4.z, dw = z4.w - c4.w;
            lsum += dx * dx + dy * dy + dz * dz + dw * dw;
        }
    }
#pragma unroll
    for (int off = 32; off >= 1; off >>= 1) lsum += __shfl_down(lsum, off, 64);
    if ((tid & 63) == 0) lred[tid >> 6] = lsum;
    __syncthreads();
    if (tid == 0) atomicAdd(&ws[OFF_LOSS], lred[0] + lred[1] + lred[2] + lred[3]);
}

// ---------------- cluster-size EMA + n + loss + prefix-sum of counts ----------------
__global__ __launch_bounds__(1024) void finalize_a(const float* __restrict__ ema_cs,
                                                   float* __restrict__ ws,
                                                   float* __restrict__ out_ncs,
                                                   float* __restrict__ out_loss) {
    __shared__ float wred[16];
    __shared__ int   wscan[16];
    const int tid = threadIdx.x, lane = tid & 63, w = tid >> 6;

    float cnt = ws[OFF_CNT + tid];
    float ncs = 0.99f * ema_cs[tid] + 0.01f * cnt;
    out_ncs[tid] = ncs;

    float s = ncs;
#pragma unroll
    for (int off = 32; off >= 1; off >>= 1) s += __shfl_down(s, off, 64);

    int v = (int)cnt;
    int x = v;
#pragma unroll
    for (int off = 1; off < 64; off <<= 1) {
        int o = __shfl_up(x, off, 64);
        if (lane >= off) x += o;
    }
    if (lane == 63) wscan[w] = x;
    if (lane == 0)  wred[w]  = s;
    __syncthreads();
    if (tid == 0) {
        float n = 0.f;
#pragma unroll
        for (int k = 0; k < 16; ++k) n += wred[k];
        ws[OFF_N] = n;
        out_loss[0] = 0.5f * ws[OFF_LOSS] / 8388608.0f;
        int run = 0;
#pragma unroll
        for (int k = 0; k < 16; ++k) { int t = wscan[k]; wscan[k] = run; run += t; }
    }
    __syncthreads();
    ((int*)ws)[OFF_BASE + tid] = x - v + wscan[w];   // exclusive scan of counts
}

// ---------------- scatter row ids into per-code buckets ----------------
__global__ __launch_bounds__(256) void scatter_rows(float* __restrict__ ws) {
    int row = blockIdx.x * 256 + threadIdx.x;
    int* wsi = (int*)ws;
    int e = wsi[OFF_IDX + row];
    int slot = atomicAdd(&wsi[OFF_FILL + e], 1);
    wsi[OFF_BUCKET + wsi[OFF_BASE + e] + slot] = row;
}

// ---------------- per-code embed-sum + EMA + new codebook ----------------
__global__ __launch_bounds__(256) void update_codebook(const float* __restrict__ z,
                                                       const float* __restrict__ ema_sum,
                                                       const float* __restrict__ ws,
                                                       const float* __restrict__ out_ncs,
                                                       float* __restrict__ out_nes,
                                                       float* __restrict__ out_ncb) {
    const int e = blockIdx.x, d = threadIdx.x;
    const int* wsi = (const int*)ws;
    const int cnt = (int)ws[OFF_CNT + e];
    const int b   = wsi[OFF_BASE + e];
    float acc = 0.f;
    for (int i = 0; i < cnt; ++i) {
        int row = wsi[OFF_BUCKET + b + i];       // wave-uniform -> broadcast load
        acc += z[(size_t)row * DIM + d];         // coalesced 1KB row read
    }
    float nes = 0.99f * ema_sum[(size_t)e * DIM + d] + 0.01f * acc;
    out_nes[(size_t)e * DIM + d] = nes;
    float ncs = out_ncs[e];
    float n   = ws[OFF_N];
    float sm  = (ncs + 1e-5f) / (n + NE * 1e-5f) * n;
    out_ncb[(size_t)e * DIM + d] = nes / sm;
}

extern "C" void kernel_launch(void* const* d_in, const int* in_sizes, int n_in,
                              void* d_out, int out_size, void* d_ws, size_t ws_size,
                              hipStream_t stream) {
    const float* z_e      = (const float*)d_in[0];
    const float* codebook = (const float*)d_in[1];
    const float* ema_cs   = (const float*)d_in[2];
    const float* ema_sum  = (const float*)d_in[3];
    float* out = (float*)d_out;
    float* ws  = (float*)d_ws;

    hipMemsetAsync(ws + OFF_LOSS, 0, sizeof(float), stream);
    hipMemsetAsync(ws + OFF_CNT, 0, 2048 * sizeof(float), stream);     // CNT + FILL
    hipMemsetAsync(ws + OFF_KEY, 0xFF, (size_t)N_ROWS * 8, stream);    // keys = u64 max

    csq_kernel<<<NE / 4, 256, 0, stream>>>(codebook, ws + OFF_CSQ);

    gemm_argmin<<<dim3(N_ROWS / 128, NE / 128), 256, 0, stream>>>(
        z_e, codebook, ws + OFF_CSQ, (u64*)(ws + OFF_KEY));

    combine_gather<<<N_ROWS / 64, 256, 0, stream>>>(z_e, codebook,
                                                    out + O_ZQ, out + O_IDX, ws);

    finalize_a<<<1, 1024, 0, stream>>>(ema_cs, ws, out + O_NCS, out + O_LOSS);

    scatter_rows<<<N_ROWS / 256, 256, 0, stream>>>(ws);

    update_codebook<<<NE, 256, 0, stream>>>(z_e, ema_sum, ws, out + O_NCS,
                                            out + O_NES, out + O_NCB);
}

// Round 3
// 390.985 us; speedup vs baseline: 3.3339x; 1.7708x over previous
//
#include <hip/hip_runtime.h>

typedef unsigned long long u64;
typedef unsigned int u32;

#define N_ROWS 32768
#define DIM    256
#define NE     1024

// out layout (float offsets)
#define O_ZQ   0
#define O_LOSS 8388608
#define O_IDX  8388609
#define O_NCB  8421377
#define O_NCS  8683521
#define O_NES  8684545

// ws layout (float offsets)
#define OFF_LOSS   0
#define OFF_N      1
#define OFF_CSQ    64
#define OFF_CNT    1088
#define OFF_FILL   2112      // int[1024]
#define OFF_BASE   3200      // int[1024]
#define OFF_IDX    4224      // int[32768]
#define OFF_BUCKET 36992     // int[32768]
#define OFF_KEY    69888     // u64[32768] (byte offset 279552, 8B aligned)

// ---------------- codebook squared norms ----------------
__global__ __launch_bounds__(256) void csq_kernel(const float* __restrict__ cb,
                                                  float* __restrict__ csq) {
    int e    = blockIdx.x * 4 + (threadIdx.x >> 6);
    int lane = threadIdx.x & 63;
    float4 v = *(const float4*)(cb + (size_t)e * DIM + lane * 4);
    float s  = v.x * v.x + v.y * v.y + v.z * v.z + v.w * v.w;
#pragma unroll
    for (int off = 32; off >= 1; off >>= 1) s += __shfl_down(s, off, 64);
    if (lane == 0) csq[e] = s;
}

// ---------------- GEMM + per-row argmin via packed u64 atomicMin ----------------
__global__ __launch_bounds__(256, 4) void gemm_argmin(const float* __restrict__ z,
                                                      const float* __restrict__ cb,
                                                      const float* __restrict__ ws_csq,
                                                      u64* __restrict__ keys) {
    __shared__ float xs[32][128];   // K-major x tile chunk, 16 KB
    __shared__ float cs[32][128];   // K-major code tile chunk, 16 KB

    const int tid  = threadIdx.x;
    const int row0 = blockIdx.x * 128;
    const int e0   = blockIdx.y * 128;
    const int tx   = tid & 15, ty = tid >> 4;
    const int skq  = tid & 7,  sr = tid >> 3;    // staging: float4-idx along k, row group

    float acc[8][8];
#pragma unroll
    for (int i = 0; i < 8; ++i)
#pragma unroll
        for (int j = 0; j < 8; ++j) acc[i][j] = 0.f;

    for (int kc = 0; kc < DIM; kc += 32) {
        __syncthreads();
        // stage x chunk (transpose to K-major; 8-lane-contiguous 128B global segments)
#pragma unroll
        for (int j = 0; j < 4; ++j) {
            int r = sr + j * 32;
            float4 v = *(const float4*)(z + (size_t)(row0 + r) * DIM + kc + skq * 4);
            xs[skq * 4 + 0][r] = v.x; xs[skq * 4 + 1][r] = v.y;
            xs[skq * 4 + 2][r] = v.z; xs[skq * 4 + 3][r] = v.w;
        }
        // stage codebook chunk
#pragma unroll
        for (int j = 0; j < 4; ++j) {
            int c = sr + j * 32;
            float4 v = *(const float4*)(cb + (size_t)(e0 + c) * DIM + kc + skq * 4);
            cs[skq * 4 + 0][c] = v.x; cs[skq * 4 + 1][c] = v.y;
            cs[skq * 4 + 2][c] = v.z; cs[skq * 4 + 3][c] = v.w;
        }
        __syncthreads();
#pragma unroll 2
        for (int k = 0; k < 32; ++k) {
            float4 xa  = *(const float4*)(&xs[k][ty * 4]);        // broadcast over tx
            float4 xb  = *(const float4*)(&xs[k][64 + ty * 4]);
            float4 ca  = *(const float4*)(&cs[k][tx * 4]);        // 2-way (free) over lanes
            float4 cb4 = *(const float4*)(&cs[k][64 + tx * 4]);
            float xr[8] = {xa.x, xa.y, xa.z, xa.w, xb.x, xb.y, xb.z, xb.w};
            float cc[8] = {ca.x, ca.y, ca.z, ca.w, cb4.x, cb4.y, cb4.z, cb4.w};
#pragma unroll
            for (int i = 0; i < 8; ++i)
#pragma unroll
                for (int j = 0; j < 8; ++j)
                    acc[i][j] = fmaf(xr[i], cc[j], acc[i][j]);
        }
    }

    // distances (z_sq term constant per row: omitted) + lex argmin
    float cq[8];
#pragma unroll
    for (int j = 0; j < 8; ++j) {
        int e = e0 + ((j < 4) ? tx * 4 + j : 64 + tx * 4 + (j - 4));
        cq[j] = ws_csq[e];
    }
#pragma unroll
    for (int i = 0; i < 8; ++i) {
        float bv = 3.4e38f; int bi = 0x7fffffff;
#pragma unroll
        for (int j = 0; j < 8; ++j) {
            int e = e0 + ((j < 4) ? tx * 4 + j : 64 + tx * 4 + (j - 4));
            float d = fmaf(-2.0f, acc[i][j], cq[j]);
            if (d < bv || (d == bv && e < bi)) { bv = d; bi = e; }
        }
        // lex (val,idx) min across the 16 tx-lanes of this row group
#pragma unroll
        for (int off = 8; off >= 1; off >>= 1) {
            float ov = __shfl_xor(bv, off, 16);
            int   oi = __shfl_xor(bi, off, 16);
            if (ov < bv || (ov == bv && oi < bi)) { bv = ov; bi = oi; }
        }
        if (tx == 0) {
            int r = row0 + ((i < 4) ? ty * 4 + i : 64 + ty * 4 + (i - 4));
            u32 b = __float_as_uint(bv);
            u32 m = (b & 0x80000000u) ? ~b : (b | 0x80000000u);  // order-preserving map
            u64 key = ((u64)m << 10) | (u32)bi;                  // exact (val, idx) lex order
            atomicMin(&keys[r], key);
        }
    }
}

// ---------------- combine argmin + gather z_q + commitment loss + counts ----------------
__global__ __launch_bounds__(256) void combine_gather(const float* __restrict__ z,
                                                      const float* __restrict__ cb,
                                                      float* __restrict__ out_zq,
                                                      float* __restrict__ out_idx,
                                                      float* __restrict__ ws) {
    __shared__ int   sidx[64];
    __shared__ float lred[4];
    const int tid  = threadIdx.x;
    const int row0 = blockIdx.x * 64;

    if (tid < 64) {
        const u64* keys = (const u64*)(ws + OFF_KEY);
        u64 key = keys[row0 + tid];
        int idx = (int)(key & 1023u);
        sidx[tid] = idx;
        out_idx[row0 + tid] = (float)idx;
        ((int*)ws)[OFF_IDX + row0 + tid] = idx;
        atomicAdd(&ws[OFF_CNT + idx], 1.0f);
    }
    __syncthreads();

    float lsum = 0.f;
    {
        int r = tid >> 2, part = tid & 3;
        int e = sidx[r];
        const float4* crow = (const float4*)(cb + (size_t)e * DIM + part * 64);
        const float4* zrow = (const float4*)(z + (size_t)(row0 + r) * DIM + part * 64);
        float4*       qrow = (float4*)(out_zq + (size_t)(row0 + r) * DIM + part * 64);
#pragma unroll
        for (int j = 0; j < 16; ++j) {
            float4 c4 = crow[j];
            float4 z4 = zrow[j];
            qrow[j] = c4;
            float dx = z4.x - c4.x, dy = z4.y - c4.y;
            float dz = z4.z - c4.z, dw = z4.w - c4.w;
            lsum += dx * dx + dy * dy + dz * dz + dw * dw;
        }
    }
#pragma unroll
    for (int off = 32; off >= 1; off >>= 1) lsum += __shfl_down(lsum, off, 64);
    if ((tid & 63) == 0) lred[tid >> 6] = lsum;
    __syncthreads();
    if (tid == 0) atomicAdd(&ws[OFF_LOSS], lred[0] + lred[1] + lred[2] + lred[3]);
}

// ---------------- cluster-size EMA + n + loss + prefix-sum of counts ----------------
__global__ __launch_bounds__(1024) void finalize_a(const float* __restrict__ ema_cs,
                                                   float* __restrict__ ws,
                                                   float* __restrict__ out_ncs,
                                                   float* __restrict__ out_loss) {
    __shared__ float wred[16];
    __shared__ int   wscan[16];
    const int tid = threadIdx.x, lane = tid & 63, w = tid >> 6;

    float cnt = ws[OFF_CNT + tid];
    float ncs = 0.99f * ema_cs[tid] + 0.01f * cnt;
    out_ncs[tid] = ncs;

    float s = ncs;
#pragma unroll
    for (int off = 32; off >= 1; off >>= 1) s += __shfl_down(s, off, 64);

    int v = (int)cnt;
    int x = v;
#pragma unroll
    for (int off = 1; off < 64; off <<= 1) {
        int o = __shfl_up(x, off, 64);
        if (lane >= off) x += o;
    }
    if (lane == 63) wscan[w] = x;
    if (lane == 0)  wred[w]  = s;
    __syncthreads();
    if (tid == 0) {
        float n = 0.f;
#pragma unroll
        for (int k = 0; k < 16; ++k) n += wred[k];
        ws[OFF_N] = n;
        out_loss[0] = 0.5f * ws[OFF_LOSS] / 8388608.0f;
        int run = 0;
#pragma unroll
        for (int k = 0; k < 16; ++k) { int t = wscan[k]; wscan[k] = run; run += t; }
    }
    __syncthreads();
    ((int*)ws)[OFF_BASE + tid] = x - v + wscan[w];   // exclusive scan of counts
}

// ---------------- scatter row ids into per-code buckets ----------------
__global__ __launch_bounds__(256) void scatter_rows(float* __restrict__ ws) {
    int row = blockIdx.x * 256 + threadIdx.x;
    int* wsi = (int*)ws;
    int e = wsi[OFF_IDX + row];
    int slot = atomicAdd(&wsi[OFF_FILL + e], 1);
    wsi[OFF_BUCKET + wsi[OFF_BASE + e] + slot] = row;
}

// ---------------- work-balanced segmented embed-sum over bucket array ----------------
// Block b owns bucket positions [b*32, b*32+32). Codes are non-decreasing along
// the bucket array, so each block flushes at most a handful of segments.
__global__ __launch_bounds__(256) void seg_reduce(const float* __restrict__ z,
                                                  const float* __restrict__ ws,
                                                  float* __restrict__ bsum) {
    __shared__ int srow[32];
    __shared__ int scode[32];
    const int tid = threadIdx.x;
    const int p0  = blockIdx.x * 32;
    const int* wsi = (const int*)ws;

    if (tid < 32) {
        int row = wsi[OFF_BUCKET + p0 + tid];
        srow[tid]  = row;
        scode[tid] = wsi[OFF_IDX + row];
    }
    __syncthreads();

    const int d = tid;               // 256 threads = one full row, coalesced
    float acc = 0.f;
    int prev = scode[0];
#pragma unroll 4
    for (int i = 0; i < 32; ++i) {
        int e = scode[i];            // wave-uniform
        if (e != prev) {             // uniform branch: flush finished segment
            atomicAdd(&bsum[(size_t)prev * DIM + d], acc);
            acc = 0.f;
            prev = e;
        }
        acc += z[(size_t)srow[i] * DIM + d];
    }
    atomicAdd(&bsum[(size_t)prev * DIM + d], acc);
}

// ---------------- EMA + smoothed codebook (bsum accumulated in out_nes) ----------------
__global__ __launch_bounds__(256) void finalize_b(const float* __restrict__ ema_sum,
                                                  const float* __restrict__ ws,
                                                  const float* __restrict__ out_ncs,
                                                  float* __restrict__ out_nes,
                                                  float* __restrict__ out_ncb) {
    const int e = blockIdx.x, d = threadIdx.x;
    const size_t i = (size_t)e * DIM + d;
    float bsum = out_nes[i];                       // batch segment sum (atomics landed here)
    float nes  = 0.99f * ema_sum[i] + 0.01f * bsum;
    out_nes[i] = nes;
    float ncs = out_ncs[e];
    float n   = ws[OFF_N];
    float sm  = (ncs + 1e-5f) / (n + NE * 1e-5f) * n;
    out_ncb[i] = nes / sm;
}

extern "C" void kernel_launch(void* const* d_in, const int* in_sizes, int n_in,
                              void* d_out, int out_size, void* d_ws, size_t ws_size,
                              hipStream_t stream) {
    const float* z_e      = (const float*)d_in[0];
    const float* codebook = (const float*)d_in[1];
    const float* ema_cs   = (const float*)d_in[2];
    const float* ema_sum  = (const float*)d_in[3];
    float* out = (float*)d_out;
    float* ws  = (float*)d_ws;

    hipMemsetAsync(ws + OFF_LOSS, 0, sizeof(float), stream);
    hipMemsetAsync(ws + OFF_CNT, 0, 2048 * sizeof(float), stream);     // CNT + FILL
    hipMemsetAsync(ws + OFF_KEY, 0xFF, (size_t)N_ROWS * 8, stream);    // keys = u64 max
    hipMemsetAsync(out + O_NES, 0, (size_t)NE * DIM * sizeof(float), stream);  // bsum accumulator

    csq_kernel<<<NE / 4, 256, 0, stream>>>(codebook, ws + OFF_CSQ);

    gemm_argmin<<<dim3(N_ROWS / 128, NE / 128), 256, 0, stream>>>(
        z_e, codebook, ws + OFF_CSQ, (u64*)(ws + OFF_KEY));

    combine_gather<<<N_ROWS / 64, 256, 0, stream>>>(z_e, codebook,
                                                    out + O_ZQ, out + O_IDX, ws);

    finalize_a<<<1, 1024, 0, stream>>>(ema_cs, ws, out + O_NCS, out + O_LOSS);

    scatter_rows<<<N_ROWS / 256, 256, 0, stream>>>(ws);

    seg_reduce<<<N_ROWS / 32, 256, 0, stream>>>(z_e, ws, out + O_NES);

    finalize_b<<<NE, 256, 0, stream>>>(ema_sum, ws, out + O_NCS,
                                       out + O_NES, out + O_NCB);
}

// Round 5
// 228.525 us; speedup vs baseline: 5.7040x; 1.7109x over previous
//
#include <hip/hip_runtime.h>

typedef unsigned long long u64;
typedef unsigned int u32;
typedef __attribute__((ext_vector_type(8))) short short8;
typedef __attribute__((ext_vector_type(4))) float f32x4;

#define N_ROWS 32768
#define DIM    256
#define NE     1024

// out layout (float offsets)
#define O_ZQ   0
#define O_LOSS 8388608
#define O_IDX  8388609
#define O_NCB  8421377
#define O_NCS  8683521
#define O_NES  8684545

// ws layout (float offsets)
#define OFF_LOSS   0
#define OFF_N      1
#define OFF_CSQ    64
#define OFF_CNT    1088
#define OFF_FILL   2112      // int[1024]
#define OFF_BASE   3200      // int[1024]
#define OFF_IDX    4224      // int[32768]
#define OFF_BUCKET 36992     // int[32768]
#define OFF_KEY    69888     // u64[32768]
#define OFF_CB16   135424    // ushort[262144] = 512KB bf16 codebook

#define MARGIN   2.0f
#define LIST_CAP 3072

__device__ __forceinline__ unsigned short bf16rne(float x) {
    u32 b = __float_as_uint(x);
    return (unsigned short)((b + 0x7FFFu + ((b >> 16) & 1u)) >> 16);
}

// ---------------- prep: zero stats/keys/bsum + csq + bf16 codebook ----------------
__global__ __launch_bounds__(256) void prep_kernel(const float* __restrict__ cb,
                                                   float* __restrict__ ws,
                                                   float* __restrict__ out_nes) {
    const int tid = threadIdx.x, b = blockIdx.x;
    const int g = b * 256 + tid;

    // zero bsum accumulator (out is re-poisoned 0xAA each launch); O_NES is odd -> scalar
#pragma unroll
    for (int j = 0; j < 4; ++j) out_nes[g + j * 65536] = 0.f;
    if (g < N_ROWS) ((u64*)(ws + OFF_KEY))[g] = ~0ull;
    if (g < 2048) ws[OFF_CNT + g] = 0.f;           // CNT + FILL
    if (g == 0) ws[OFF_LOSS] = 0.f;

    // csq + bf16 conversion: block handles 4 codebook rows
    const int e = b * 4 + (tid >> 6);
    const int lane = tid & 63;
    float4 v = *(const float4*)(cb + (size_t)e * DIM + lane * 4);
    ushort4 h;
    h.x = bf16rne(v.x); h.y = bf16rne(v.y); h.z = bf16rne(v.z); h.w = bf16rne(v.w);
    *(ushort4*)((unsigned short*)(ws + OFF_CB16) + (size_t)e * DIM + lane * 4) = h;
    float s = v.x * v.x + v.y * v.y + v.z * v.z + v.w * v.w;
#pragma unroll
    for (int off = 32; off >= 1; off >>= 1) s += __shfl_down(s, off, 64);
    if (lane == 0) ws[OFF_CSQ + e] = s;
}

// ---------------- main: MFMA distances + margin refine + gather + stats ----------------
__global__ __launch_bounds__(512, 2) void vq_main(const float* __restrict__ z,
                                                  const float* __restrict__ cb,
                                                  float* __restrict__ ws,
                                                  float* __restrict__ out_zq,
                                                  float* __restrict__ out_idx) {
    __shared__ unsigned short zs[128][256];   // 64KB, cols XOR-swizzled by 8*(row&15)
    __shared__ unsigned short cbs[256][128];  // 64KB, cols XOR-swizzled by 8*(row&15)
    __shared__ float csq_s[NE];               // 4KB
    __shared__ u32   list[LIST_CAP];          // 12KB
    __shared__ int   lcnt;
    __shared__ int   sidx[128];
    __shared__ float lred[8];

    const int tid  = threadIdx.x;
    const int row0 = blockIdx.x * 128;
    const unsigned short* cb16 = (const unsigned short*)(ws + OFF_CB16);
    u64* keys = (u64*)(ws + OFF_KEY);

    if (tid == 0) lcnt = 0;
    csq_s[tid]       = ws[OFF_CSQ + tid];
    csq_s[tid + 512] = ws[OFF_CSQ + tid + 512];

    // ---- stage z tile f32 -> bf16 (coalesced 32B/lane reads, swizzled ds writes)
#pragma unroll
    for (int sweep = 0; sweep < 8; ++sweep) {
        int fi = sweep * 4096 + tid * 8;
        int r = fi >> 8, c = fi & 255;
        const float4* src = (const float4*)(z + (size_t)row0 * DIM + fi);
        float4 v0 = src[0], v1 = src[1];
        short8 p;
        p[0] = (short)bf16rne(v0.x); p[1] = (short)bf16rne(v0.y);
        p[2] = (short)bf16rne(v0.z); p[3] = (short)bf16rne(v0.w);
        p[4] = (short)bf16rne(v1.x); p[5] = (short)bf16rne(v1.y);
        p[6] = (short)bf16rne(v1.z); p[7] = (short)bf16rne(v1.w);
        *(short8*)&zs[r][c ^ (8 * (r & 15))] = p;
    }

    const int wid = tid >> 6, lane = tid & 63;
    const int wm = wid >> 2, wn = wid & 3;          // wave grid 2M x 4N
    const int l15 = lane & 15, l4 = lane >> 4;
    const int arow_base = wm * 64;
    const int swz = 8 * l15;                        // row&15 == l15 for all frag rows

    float runmin[4][4];
#pragma unroll
    for (int m = 0; m < 4; ++m)
#pragma unroll
        for (int rg = 0; rg < 4; ++rg) runmin[m][rg] = 3.4e38f;

    for (int chunk = 0; chunk < 4; ++chunk) {
        const int e0 = chunk * 256;
        f32x4 acc[4][4];
#pragma unroll
        for (int m = 0; m < 4; ++m)
#pragma unroll
            for (int n = 0; n < 4; ++n) acc[m][n] = (f32x4){0.f, 0.f, 0.f, 0.f};

        for (int kh = 0; kh < 2; ++kh) {
            __syncthreads();
            // stage cbs: 256 codes x 128 k-half (bf16, already converted)
#pragma unroll
            for (int sweep = 0; sweep < 8; ++sweep) {
                int r  = sweep * 32 + (tid >> 4);
                int lk = (tid & 15) * 8;
                short8 v = *(const short8*)(cb16 + (size_t)(e0 + r) * DIM + kh * 128 + lk);
                *(short8*)&cbs[r][lk ^ (8 * (r & 15))] = v;
            }
            __syncthreads();
#pragma unroll
            for (int ks = 0; ks < 4; ++ks) {
                short8 a[4], bfr[4];
                int acol = kh * 128 + ks * 32 + 8 * l4;
                int bcol = ks * 32 + 8 * l4;
#pragma unroll
                for (int m = 0; m < 4; ++m)
                    a[m] = *(const short8*)&zs[arow_base + m * 16 + l15][acol ^ swz];
#pragma unroll
                for (int n = 0; n < 4; ++n)
                    bfr[n] = *(const short8*)&cbs[wn * 64 + n * 16 + l15][bcol ^ swz];
#pragma unroll
                for (int m = 0; m < 4; ++m)
#pragma unroll
                    for (int n = 0; n < 4; ++n)
                        acc[m][n] = __builtin_amdgcn_mfma_f32_16x16x32_bf16(
                            a[m], bfr[n], acc[m][n], 0, 0, 0);
            }
        }
        // ---- chunk epilogue: per-row running min + margin push
        float cq[4];
#pragma unroll
        for (int n = 0; n < 4; ++n) cq[n] = csq_s[e0 + wn * 64 + n * 16 + l15];
#pragma unroll
        for (int m = 0; m < 4; ++m) {
#pragma unroll
            for (int rg = 0; rg < 4; ++rg) {
                float cmin = 3.4e38f;
#pragma unroll
                for (int n = 0; n < 4; ++n)
                    cmin = fminf(cmin, fmaf(-2.0f, acc[m][n][rg], cq[n]));
#pragma unroll
                for (int off = 1; off <= 8; off <<= 1)
                    cmin = fminf(cmin, __shfl_xor(cmin, off, 16));
                runmin[m][rg] = fminf(runmin[m][rg], cmin);
                float thr = runmin[m][rg] + MARGIN;
                int lrow = arow_base + m * 16 + l4 * 4 + rg;
#pragma unroll
                for (int n = 0; n < 4; ++n) {
                    float d = fmaf(-2.0f, acc[m][n][rg], cq[n]);
                    if (d <= thr) {
                        int slot = atomicAdd(&lcnt, 1);
                        if (slot < LIST_CAP)
                            list[slot] = ((u32)lrow << 10) |
                                         (u32)(e0 + wn * 64 + n * 16 + l15);
                    }
                }
            }
        }
    }
    __syncthreads();

    // ---- exact f32 refinement of margin candidates (16-lane groups)
    int nlist = lcnt < LIST_CAP ? lcnt : LIST_CAP;
    const int grp = tid >> 4, gl = tid & 15;
    for (int i = grp; i < nlist; i += 32) {
        u32 ent = list[i];
        int lrow = ent >> 10, code = ent & 1023;
        const float* zr = z + (size_t)(row0 + lrow) * DIM + gl * 16;
        const float* cr = cb + (size_t)code * DIM + gl * 16;
        float s = 0.f;
#pragma unroll
        for (int j = 0; j < 4; ++j) {
            float4 zv = ((const float4*)zr)[j];
            float4 cv = ((const float4*)cr)[j];
            s = fmaf(zv.x, cv.x, s); s = fmaf(zv.y, cv.y, s);
            s = fmaf(zv.z, cv.z, s); s = fmaf(zv.w, cv.w, s);
        }
#pragma unroll
        for (int off = 1; off <= 8; off <<= 1) s += __shfl_xor(s, off, 16);
        if (gl == 0) {
            float d = fmaf(-2.0f, s, csq_s[code]);
            u32 bb = __float_as_uint(d);
            u32 mm = (bb & 0x80000000u) ? ~bb : (bb | 0x80000000u);
            u64 key = ((u64)mm << 10) | (u32)code;
            atomicMin(&keys[row0 + lrow], key);
        }
    }
    __syncthreads();

    // ---- winners -> idx/counts; gather z_q; commitment loss
    if (tid < 128) {
        u64 key = atomicMin(&keys[row0 + tid], ~0ull);   // L2-coherent readback
        int idx = (int)(key & 1023u);
        sidx[tid] = idx;
        out_idx[row0 + tid] = (float)idx;
        ((int*)ws)[OFF_IDX + row0 + tid] = idx;
        atomicAdd(&ws[OFF_CNT + idx], 1.0f);
    }
    __syncthreads();

    float lsum = 0.f;
    {
        int r = tid >> 2, part = tid & 3;
        int e = sidx[r];
        const float4* crow = (const float4*)(cb + (size_t)e * DIM + part * 64);
        const float4* zrow = (const float4*)(z + (size_t)(row0 + r) * DIM + part * 64);
        float4*       qrow = (float4*)(out_zq + (size_t)(row0 + r) * DIM + part * 64);
#pragma unroll
        for (int j = 0; j < 16; ++j) {
            float4 c4 = crow[j];
            float4 z4 = zrow[j];
            qrow[j] = c4;
            float dx = z4.x - c4.x, dy = z4.y - c4.y;
            float dz = z4.z - c4.z, dw = z4.w - c4.w;
            lsum += dx * dx + dy * dy + dz * dz + dw * dw;
        }
    }
#pragma unroll
    for (int off = 32; off >= 1; off >>= 1) lsum += __shfl_down(lsum, off, 64);
    if ((tid & 63) == 0) lred[tid >> 6] = lsum;
    __syncthreads();
    if (tid == 0) {
        float t = 0.f;
#pragma unroll
        for (int w = 0; w < 8; ++w) t += lred[w];
        atomicAdd(&ws[OFF_LOSS], t);
    }
}

// ---------------- cluster-size EMA + n + loss + prefix-sum of counts ----------------
__global__ __launch_bounds__(1024) void finalize_a(const float* __restrict__ ema_cs,
                                                   float* __restrict__ ws,
                                                   float* __restrict__ out_ncs,
                                                   float* __restrict__ out_loss) {
    __shared__ float wred[16];
    __shared__ int   wscan[16];
    const int tid = threadIdx.x, lane = tid & 63, w = tid >> 6;

    float cnt = ws[OFF_CNT + tid];
    float ncs = 0.99f * ema_cs[tid] + 0.01f * cnt;
    out_ncs[tid] = ncs;

    float s = ncs;
#pragma unroll
    for (int off = 32; off >= 1; off >>= 1) s += __shfl_down(s, off, 64);

    int v = (int)cnt;
    int x = v;
#pragma unroll
    for (int off = 1; off < 64; off <<= 1) {
        int o = __shfl_up(x, off, 64);
        if (lane >= off) x += o;
    }
    if (lane == 63) wscan[w] = x;
    if (lane == 0)  wred[w]  = s;
    __syncthreads();
    if (tid == 0) {
        float n = 0.f;
#pragma unroll
        for (int k = 0; k < 16; ++k) n += wred[k];
        ws[OFF_N] = n;
        out_loss[0] = 0.5f * ws[OFF_LOSS] / 8388608.0f;
        int run = 0;
#pragma unroll
        for (int k = 0; k < 16; ++k) { int t = wscan[k]; wscan[k] = run; run += t; }
    }
    __syncthreads();
    ((int*)ws)[OFF_BASE + tid] = x - v + wscan[w];   // exclusive scan of counts
}

// ---------------- scatter row ids into per-code buckets ----------------
__global__ __launch_bounds__(256) void scatter_rows(float* __restrict__ ws) {
    int row = blockIdx.x * 256 + threadIdx.x;
    int* wsi = (int*)ws;
    int e = wsi[OFF_IDX + row];
    int slot = atomicAdd(&wsi[OFF_FILL + e], 1);
    wsi[OFF_BUCKET + wsi[OFF_BASE + e] + slot] = row;
}

// ---------------- work-balanced segmented embed-sum over bucket array ----------------
__global__ __launch_bounds__(256) void seg_reduce(const float* __restrict__ z,
                                                  const float* __restrict__ ws,
                                                  float* __restrict__ bsum) {
    __shared__ int srow[32];
    __shared__ int scode[32];
    const int tid = threadIdx.x;
    const int p0  = blockIdx.x * 32;
    const int* wsi = (const int*)ws;

    if (tid < 32) {
        int row = wsi[OFF_BUCKET + p0 + tid];
        srow[tid]  = row;
        scode[tid] = wsi[OFF_IDX + row];
    }
    __syncthreads();

    const int d = tid;
    float acc = 0.f;
    int prev = scode[0];
#pragma unroll 4
    for (int i = 0; i < 32; ++i) {
        int e = scode[i];
        if (e != prev) {
            atomicAdd(&bsum[(size_t)prev * DIM + d], acc);
            acc = 0.f;
            prev = e;
        }
        acc += z[(size_t)srow[i] * DIM + d];
    }
    atomicAdd(&bsum[(size_t)prev * DIM + d], acc);
}

// ---------------- EMA + smoothed codebook (bsum accumulated in out_nes) ----------------
__global__ __launch_bounds__(256) void finalize_b(const float* __restrict__ ema_sum,
                                                  const float* __restrict__ ws,
                                                  const float* __restrict__ out_ncs,
                                                  float* __restrict__ out_nes,
                                                  float* __restrict__ out_ncb) {
    const int e = blockIdx.x, d = threadIdx.x;
    const size_t i = (size_t)e * DIM + d;
    float bsum = out_nes[i];
    float nes  = 0.99f * ema_sum[i] + 0.01f * bsum;
    out_nes[i] = nes;
    float ncs = out_ncs[e];
    float n   = ws[OFF_N];
    float sm  = (ncs + 1e-5f) / (n + NE * 1e-5f) * n;
    out_ncb[i] = nes / sm;
}

extern "C" void kernel_launch(void* const* d_in, const int* in_sizes, int n_in,
                              void* d_out, int out_size, void* d_ws, size_t ws_size,
                              hipStream_t stream) {
    const float* z_e      = (const float*)d_in[0];
    const float* codebook = (const float*)d_in[1];
    const float* ema_cs   = (const float*)d_in[2];
    const float* ema_sum  = (const float*)d_in[3];
    float* out = (float*)d_out;
    float* ws  = (float*)d_ws;

    prep_kernel<<<256, 256, 0, stream>>>(codebook, ws, out + O_NES);

    vq_main<<<256, 512, 0, stream>>>(z_e, codebook, ws, out + O_ZQ, out + O_IDX);

    finalize_a<<<1, 1024, 0, stream>>>(ema_cs, ws, out + O_NCS, out + O_LOSS);

    scatter_rows<<<N_ROWS / 256, 256, 0, stream>>>(ws);

    seg_reduce<<<N_ROWS / 32, 256, 0, stream>>>(z_e, ws, out + O_NES);

    finalize_b<<<NE, 256, 0, stream>>>(ema_sum, ws, out + O_NCS,
                                       out + O_NES, out + O_NCB);
}